// Round 1
// baseline (799.681 us; speedup 1.0000x reference)
//
#include <hip/hip_runtime.h>

// LaplacianLoss: out[b] = sum_{n,d} ( sum_m L[n,m] * x[b,m,d] )^2
// x: (B=4, NV=10242, 3) fp32;  L: (NV, NV) fp32 dense;  out: 4 fp32.
// HBM-bound on reading L (419.6 MB). Strategy: stream L rows coalesced,
// stage x in LDS as 12 SoA planes (k = b*3+d), R=4 rows per wave,
// reduce-before-square via wave shuffle, per-block partials in d_ws,
// deterministic final reduce kernel (no atomics, no d_out pre-zeroing).

#define NV   10242
#define NB   4
#define TM   1024       // m-tile staged in LDS
#define TMP  1025       // padded plane stride (breaks staging write conflicts)
#define RPW  4          // rows per wave
#define WAVES 4
#define RPB  (RPW * WAVES)   // 16 rows per block

__global__ __launch_bounds__(256, 3) void lap_main(
    const float* __restrict__ x,
    const float* __restrict__ L,
    float* __restrict__ part)
{
    __shared__ float xs[12 * TMP];       // 12 planes: xs[k*TMP + i] = x[b, m0+i, d], k=b*3+d
    __shared__ float bsum[WAVES][NB];

    const int tid  = threadIdx.x;
    const int wave = tid >> 6;
    const int lane = tid & 63;
    const int g    = blockIdx.x;
    const int row_base = g * RPB + wave * RPW;

    int nvalid = NV - row_base;
    if (nvalid > RPW) nvalid = RPW;
    if (nvalid < 0)  nvalid = 0;

    float acc[RPW][12];
#pragma unroll
    for (int r = 0; r < RPW; ++r)
#pragma unroll
        for (int k = 0; k < 12; ++k) acc[r][k] = 0.f;

    // Clamped row pointers: invalid rows compute on row NV-1, masked in epilogue.
    const float* Lrow[RPW];
#pragma unroll
    for (int r = 0; r < RPW; ++r) {
        int n = row_base + r;
        if (n >= NV) n = NV - 1;
        Lrow[r] = L + (size_t)n * NV;
    }

    for (int m0 = 0; m0 < NV; m0 += TM) {
        int len = NV - m0;
        if (len > TM) len = TM;

        __syncthreads();
        // Stage x tile: coalesced reads of 3*len contiguous floats per batch.
        for (int b = 0; b < NB; ++b) {
            const float* src = x + ((size_t)b * NV + m0) * 3;
            for (int j = tid; j < len * 3; j += 256) {
                int i = j / 3;
                int d = j - 3 * i;
                xs[(b * 3 + d) * TMP + i] = src[j];
            }
        }
        __syncthreads();

        for (int mm = lane; mm < len; mm += 64) {
            float xv[12];
#pragma unroll
            for (int k = 0; k < 12; ++k) xv[k] = xs[k * TMP + mm];
#pragma unroll
            for (int r = 0; r < RPW; ++r) {
                float lv = Lrow[r][m0 + mm];
#pragma unroll
                for (int k = 0; k < 12; ++k) acc[r][k] += lv * xv[k];
            }
        }
    }

    // Wave-level reduction of each dot product across 64 lanes (before squaring).
#pragma unroll
    for (int r = 0; r < RPW; ++r)
#pragma unroll
        for (int k = 0; k < 12; ++k) {
            float v = acc[r][k];
            for (int off = 32; off > 0; off >>= 1)
                v += __shfl_down(v, off, 64);
            acc[r][k] = v;
        }

    if (lane == 0) {
        float s[NB] = {0.f, 0.f, 0.f, 0.f};
        for (int r = 0; r < nvalid; ++r) {
#pragma unroll
            for (int b = 0; b < NB; ++b) {
                float v0 = acc[r][b * 3 + 0];
                float v1 = acc[r][b * 3 + 1];
                float v2 = acc[r][b * 3 + 2];
                s[b] += v0 * v0 + v1 * v1 + v2 * v2;
            }
        }
#pragma unroll
        for (int b = 0; b < NB; ++b) bsum[wave][b] = s[b];
    }
    __syncthreads();

    if (tid == 0) {
#pragma unroll
        for (int b = 0; b < NB; ++b) {
            part[(size_t)g * NB + b] =
                bsum[0][b] + bsum[1][b] + bsum[2][b] + bsum[3][b];
        }
    }
}

__global__ void lap_reduce(const float* __restrict__ part, int nparts,
                           float* __restrict__ out)
{
    __shared__ float sdata[256];
    const int tid = threadIdx.x;
    const int b = tid & 3;
    float s = 0.f;
    for (int i = tid >> 2; i < nparts; i += 64)
        s += part[(size_t)i * 4 + b];
    sdata[tid] = s;
    __syncthreads();
    if (tid < 4) {
        float t = 0.f;
        for (int i = tid; i < 256; i += 4) t += sdata[i];
        out[tid] = t;   // tid == b for tid < 4
    }
}

extern "C" void kernel_launch(void* const* d_in, const int* in_sizes, int n_in,
                              void* d_out, int out_size, void* d_ws, size_t ws_size,
                              hipStream_t stream)
{
    const float* x = (const float*)d_in[0];   // (4, 10242, 3)
    const float* L = (const float*)d_in[1];   // (10242, 10242)
    float* out  = (float*)d_out;              // (4,)
    float* part = (float*)d_ws;               // nblocks * 4 floats

    const int nblocks = (NV + RPB - 1) / RPB; // 641

    lap_main<<<nblocks, 256, 0, stream>>>(x, L, part);
    lap_reduce<<<1, 256, 0, stream>>>(part, nblocks, out);
}